// Round 17
// baseline (1328.398 us; speedup 1.0000x reference)
//
#include <hip/hip_runtime.h>

#define N0 262144
#define N1 65536
#define N2 16384
#define NNET 200000
#define E0 2097152
#define E1 524288
#define E2 131072
#define ECONN 800000

// ===== binned CSR build =====
#define BSH 10
#define NBK_TOT 612
#define CHK 16384
#define CBT 237

__global__ void bcount(const int* __restrict__ e0d, const int* __restrict__ e1d,
                       const int* __restrict__ e2d, const int* __restrict__ a01,
                       const int* __restrict__ a12, const int* __restrict__ cd,
                       int* __restrict__ bcnt) {
    int bb = blockIdx.x; int lb, nE, nbuk, gb; const int* dst;
    if (bb < 128)      { lb=bb;     dst=e0d; nE=E0;    nbuk=256; gb=0; }
    else if (bb < 160) { lb=bb-128; dst=e1d; nE=E1;    nbuk=64;  gb=256; }
    else if (bb < 168) { lb=bb-160; dst=e2d; nE=E2;    nbuk=16;  gb=320; }
    else if (bb < 184) { lb=bb-168; dst=a01; nE=N0;    nbuk=64;  gb=336; }
    else if (bb < 188) { lb=bb-184; dst=a12; nE=N1;    nbuk=16;  gb=400; }
    else               { lb=bb-188; dst=cd;  nE=ECONN; nbuk=196; gb=416; }
    __shared__ int h[256];
    for (int i = threadIdx.x; i < nbuk; i += 256) h[i] = 0;
    __syncthreads();
    int base = lb * CHK;
    for (int k = 0; k < CHK / 256; ++k) {
        int e = base + k * 256 + threadIdx.x;
        if (e < nE) atomicAdd(&h[dst[e] >> BSH], 1);
    }
    __syncthreads();
    for (int i = threadIdx.x; i < nbuk; i += 256)
        if (h[i]) atomicAdd(&bcnt[gb + i], h[i]);
}

__global__ __launch_bounds__(1024) void bscan(const int* __restrict__ bcnt,
                                              int* __restrict__ bs, int* __restrict__ cur) {
    __shared__ int ts[1024];
    int t = threadIdx.x;
    int v = (t < NBK_TOT) ? bcnt[t] : 0;
    ts[t] = v; __syncthreads();
    for (int off = 1; off < 1024; off <<= 1) {
        int u = (t >= off) ? ts[t - off] : 0; __syncthreads();
        ts[t] += u; __syncthreads();
    }
    if (t < NBK_TOT) {
        int ex = ts[t] - v;
        bs[t] = ex; cur[t] = ex;
        if (t == NBK_TOT - 1) bs[NBK_TOT] = ts[t];
    }
}

__global__ void bscatter(const int* e0s, const int* e0d, const int* e1s, const int* e1d,
                         const int* e2s, const int* e2d, const int* a01, const int* a12,
                         const int* cs, const int* cd,
                         int* __restrict__ cur, int2* __restrict__ bin) {
    int bb = blockIdx.x; int lb, nE, nbuk, gb; const int* dst; const int* src;
    if (bb < 128)      { lb=bb;     dst=e0d; src=e0s;     nE=E0;    nbuk=256; gb=0; }
    else if (bb < 160) { lb=bb-128; dst=e1d; src=e1s;     nE=E1;    nbuk=64;  gb=256; }
    else if (bb < 168) { lb=bb-160; dst=e2d; src=e2s;     nE=E2;    nbuk=16;  gb=320; }
    else if (bb < 184) { lb=bb-168; dst=a01; src=nullptr; nE=N0;    nbuk=64;  gb=336; }
    else if (bb < 188) { lb=bb-184; dst=a12; src=nullptr; nE=N1;    nbuk=16;  gb=400; }
    else               { lb=bb-188; dst=cd;  src=cs;      nE=ECONN; nbuk=196; gb=416; }
    __shared__ int h[256];
    __shared__ int curl[256];
    for (int i = threadIdx.x; i < nbuk; i += 256) h[i] = 0;
    __syncthreads();
    int base = lb * CHK;
    for (int k = 0; k < CHK / 256; ++k) {
        int e = base + k * 256 + threadIdx.x;
        if (e < nE) atomicAdd(&h[dst[e] >> BSH], 1);
    }
    __syncthreads();
    for (int i = threadIdx.x; i < nbuk; i += 256)
        if (h[i]) curl[i] = atomicAdd(&cur[gb + i], h[i]);
    __syncthreads();
    for (int k = 0; k < CHK / 256; ++k) {
        int e = base + k * 256 + threadIdx.x;
        if (e < nE) {
            int d = dst[e];
            int pos = atomicAdd(&curl[d >> BSH], 1);
            bin[pos] = make_int2(d, src ? src[e] : e);
        }
    }
}

// bbuild: also emits colLoc[pos] = dst&63 for the e0/e1 regions (value already
// in register -- no extra loads, 1B store).
__global__ __launch_bounds__(512) void bbuild(const int2* __restrict__ bin,
                        const int* __restrict__ bs, int* __restrict__ colAll,
                        unsigned char* __restrict__ colLoc,
                        int* rp0, int* rp1, int* rp2, int* rpA01, int* rpA12, int* rpC) {
    int g = blockIdx.x; int lb, nSeg, last; int* rp;
    if (g < 256)      { lb=g;     nSeg=N0;   rp=rp0;   last=(g==255); }
    else if (g < 320) { lb=g-256; nSeg=N1;   rp=rp1;   last=(g==319); }
    else if (g < 336) { lb=g-320; nSeg=N2;   rp=rp2;   last=(g==335); }
    else if (g < 400) { lb=g-336; nSeg=N1;   rp=rpA01; last=(g==399); }
    else if (g < 416) { lb=g-400; nSeg=N2;   rp=rpA12; last=(g==415); }
    else              { lb=g-416; nSeg=NNET; rp=rpC;   last=(g==611); }
    const int nodeBase = lb << BSH;
    const int begE = bs[g], endE = bs[g + 1];
    const bool wantLoc = (g < 320);
    __shared__ int cnt[1024];
    __shared__ int rpl[1024];
    __shared__ int ts[512];
    const int t = threadIdx.x;
    cnt[t] = 0; cnt[t + 512] = 0;
    __syncthreads();
    for (int e = begE + t; e < endE; e += 512)
        atomicAdd(&cnt[bin[e].x - nodeBase], 1);
    __syncthreads();
    int a = cnt[2 * t], b = cnt[2 * t + 1];
    int s = a + b;
    ts[t] = s; __syncthreads();
    for (int off = 1; off < 512; off <<= 1) {
        int u = (t >= off) ? ts[t - off] : 0; __syncthreads();
        ts[t] += u; __syncthreads();
    }
    int pre = ts[t] - s;
    rpl[2 * t] = pre; rpl[2 * t + 1] = pre + a;
    __syncthreads();
    int lim = nSeg - nodeBase; if (lim > 1024) lim = 1024;
    for (int i = t; i < lim; i += 512) {
        int abs0 = begE + rpl[i];
        rp[nodeBase + i] = abs0;
        cnt[i] = abs0;
    }
    if (last && t == 0) rp[nSeg] = endE;
    __syncthreads();
    for (int e = begE + t; e < endE; e += 512) {
        int2 p = bin[e];
        int pos = atomicAdd(&cnt[p.x - nodeBase], 1);
        colAll[pos] = p.y;
        if (wantLoc) colLoc[pos] = (unsigned char)(p.x & 63);
    }
}

// ===== colPair: (col | loc<<24, asgn[col]) per e0/e1 CSR slot =====
__global__ void colpair_kernel(const int* __restrict__ colAll,
                               const unsigned char* __restrict__ colLoc,
                               const int* __restrict__ a01, const int* __restrict__ a12,
                               int2* __restrict__ colPair) {
    int i = blockIdx.x * blockDim.x + threadIdx.x;   // grid covers exactly E0+E1
    int c = colAll[i];
    int up = (i < E0) ? a01[c] : a12[c];
    colPair[i] = make_int2(c | ((int)colLoc[i] << 24), up);
}

// ===== helpers =====
__device__ __forceinline__ unsigned short f2bf(float f) {   // RNE pack
    unsigned u = __float_as_uint(f);
    u += 0x7FFFu + ((u >> 16) & 1u);
    return (unsigned short)(u >> 16);
}
__device__ __forceinline__ float bf2f(unsigned short s) {
    return __uint_as_float((unsigned)s << 16);
}
__device__ __forceinline__ float4 ldbf4(const unsigned short* p) {
    ushort4 u = *reinterpret_cast<const ushort4*>(p);
    return make_float4(bf2f(u.x), bf2f(u.y), bf2f(u.z), bf2f(u.w));
}
__device__ __forceinline__ void stbf4(unsigned short* p, const float4& v) {
    ushort4 u; u.x = f2bf(v.x); u.y = f2bf(v.y); u.z = f2bf(v.z); u.w = f2bf(v.w);
    *reinterpret_cast<ushort4*>(p) = u;
}
__device__ __forceinline__ void fma4(float4& a, float s, const float4& b) {
    a.x = fmaf(s, b.x, a.x); a.y = fmaf(s, b.y, a.y);
    a.z = fmaf(s, b.z, a.z); a.w = fmaf(s, b.w, a.w);
}
__device__ __forceinline__ void red4(float4& s, int m) {
    s.x += __shfl_xor(s.x, m, 64);
    s.y += __shfl_xor(s.y, m, 64);
    s.z += __shfl_xor(s.z, m, 64);
    s.w += __shfl_xor(s.w, m, 64);
}
__device__ __forceinline__ void add4(float4& a, const float4& b) {
    a.x += b.x; a.y += b.y; a.z += b.z; a.w += b.w;
}

// ===== fp32 -> bf16 streaming convert (x0 -> xb0) =====
__global__ void cvt_bf16(const float* __restrict__ in, unsigned short* __restrict__ out, int n4) {
    int i = blockIdx.x * blockDim.x + threadIdx.x;
    if (i < n4) {
        float4 v = reinterpret_cast<const float4*>(in)[i];
        stbf4(&out[(size_t)i * 4], v);
    }
}

// ===== fused SAGE, node-major (unchanged; used for non-cat layers) =====

template<int DIN, int DOUT>
__global__ __launch_bounds__(512) void sage_b(const unsigned short* __restrict__ x,
                       const int* __restrict__ rp, const int* __restrict__ col,
                       const float* __restrict__ Ws, const float* __restrict__ Wn,
                       const float* __restrict__ bias, unsigned short* __restrict__ h, int n) {
    constexpr int NW  = 8;
    constexpr int NPB = 64;
    constexpr int L4  = DIN / 4;
    constexpr int EPA = 64 / L4;
    constexpr int SD  = DIN + 4;
    constexpr int JQ  = DOUT / 4;
    constexpr int NDP = 64 / JQ;
    constexpr int NSL = NW / NDP;
    __shared__ float xsh[NPB][SD];
    __shared__ float msh[NPB][SD];
    const int wave = threadIdx.x >> 6;
    const int lane = threadIdx.x & 63;
    const int rowlane = lane % L4;
    const int esub = lane / L4;
    const int blockBase = blockIdx.x * NPB;
#pragma unroll
    for (int k = 0; k < NW; ++k) {
        const int kk = wave * NW + k;
        const int node = blockBase + kk;
        const int beg = rp[node], end = rp[node + 1];
        float4 own = make_float4(0.f, 0.f, 0.f, 0.f);
        if (lane < L4) own = ldbf4(&x[(size_t)node * DIN + lane * 4]);
        float4 s = make_float4(0.f, 0.f, 0.f, 0.f);
#pragma unroll 2
        for (int e = beg + esub; e < end; e += EPA) {
            const int c = col[e];
            const float4 v = ldbf4(&x[(size_t)c * DIN + rowlane * 4]);
            add4(s, v);
        }
#pragma unroll
        for (int m = L4; m < 64; m <<= 1) red4(s, m);
        if (lane < L4) {
            float sc = (end > beg) ? 1.0f / (float)(end - beg) : 0.f;
            *reinterpret_cast<float4*>(&msh[kk][lane * 4]) =
                make_float4(s.x * sc, s.y * sc, s.z * sc, s.w * sc);
            *reinterpret_cast<float4*>(&xsh[kk][lane * 4]) = own;
        }
    }
    asm volatile("s_waitcnt lgkmcnt(0)" ::: "memory");
    __builtin_amdgcn_wave_barrier();
    const int jq = lane % JQ;
    const int nd = lane / JQ;
    const float4 bv = *reinterpret_cast<const float4*>(&bias[jq * 4]);
    float4 acc[NSL];
#pragma unroll
    for (int sl = 0; sl < NSL; ++sl) acc[sl] = bv;
#pragma unroll 2
    for (int i = 0; i < DIN; i += 4) {
        const float4 w0 = *reinterpret_cast<const float4*>(&Ws[(i + 0) * DOUT + jq * 4]);
        const float4 w1 = *reinterpret_cast<const float4*>(&Ws[(i + 1) * DOUT + jq * 4]);
        const float4 w2 = *reinterpret_cast<const float4*>(&Ws[(i + 2) * DOUT + jq * 4]);
        const float4 w3 = *reinterpret_cast<const float4*>(&Ws[(i + 3) * DOUT + jq * 4]);
        const float4 u0 = *reinterpret_cast<const float4*>(&Wn[(i + 0) * DOUT + jq * 4]);
        const float4 u1 = *reinterpret_cast<const float4*>(&Wn[(i + 1) * DOUT + jq * 4]);
        const float4 u2 = *reinterpret_cast<const float4*>(&Wn[(i + 2) * DOUT + jq * 4]);
        const float4 u3 = *reinterpret_cast<const float4*>(&Wn[(i + 3) * DOUT + jq * 4]);
#pragma unroll
        for (int sl = 0; sl < NSL; ++sl) {
            const int kk = wave * NW + sl * NDP + nd;
            const float4 xv = *reinterpret_cast<const float4*>(&xsh[kk][i]);
            const float4 mv = *reinterpret_cast<const float4*>(&msh[kk][i]);
            fma4(acc[sl], xv.x, w0); fma4(acc[sl], xv.y, w1);
            fma4(acc[sl], xv.z, w2); fma4(acc[sl], xv.w, w3);
            fma4(acc[sl], mv.x, u0); fma4(acc[sl], mv.y, u1);
            fma4(acc[sl], mv.z, u2); fma4(acc[sl], mv.w, u3);
        }
    }
#pragma unroll
    for (int sl = 0; sl < NSL; ++sl) {
        const int kk = wave * NW + sl * NDP + nd;
        float4 o = make_float4(tanhf(acc[sl].x), tanhf(acc[sl].y),
                               tanhf(acc[sl].z), tanhf(acc[sl].w));
        stbf4(&h[(size_t)(blockBase + kk) * DOUT + jq * 4], o);
    }
}

// ===== sage_cat, EDGE-STREAMED phase A =====
// Block owns 64 nodes and their contiguous CSR edge range. 16-lane groups
// stream edges: colPair (loc packed in .x bits 24+) -> independent row gather
// -> 4 native LDS float atomics. No per-edge read dependency -> deep MLP.

template<int DOUT>
__global__ __launch_bounds__(512) void sage_cat(const unsigned short* __restrict__ xup,
                       const int* __restrict__ asgn, const unsigned short* __restrict__ xlo,
                       const int* __restrict__ rp, const int2* __restrict__ colPair,
                       const float* __restrict__ Ws, const float* __restrict__ Wn,
                       const float* __restrict__ bias, unsigned short* __restrict__ h, int n) {
    constexpr int DIN = 64;
    constexpr int NW  = 8;
    constexpr int NPB = 64;
    constexpr int SD  = DIN + 4;
    constexpr int JQ  = DOUT / 4;
    constexpr int NDP = 64 / JQ;
    constexpr int NSL = NW / NDP;
    __shared__ float xsh[NPB][SD];
    __shared__ float msh[NPB][SD];
    __shared__ float dsc[NPB];
    const int tid = threadIdx.x;
    const int wave = tid >> 6;
    const int lane = tid & 63;
    const int blockBase = blockIdx.x * NPB;
    // --- prologue: zero msh, load own rows, compute 1/deg ---
    for (int idx = tid; idx < NPB * 16; idx += 512) {
        int node = idx >> 4, q = idx & 15;
        *reinterpret_cast<float4*>(&msh[node][q * 4]) = make_float4(0.f, 0.f, 0.f, 0.f);
        float4 own;
        if (q < 8) own = ldbf4(&xup[(size_t)asgn[blockBase + node] * 32 + q * 4]);
        else       own = ldbf4(&xlo[(size_t)(blockBase + node) * 32 + (q - 8) * 4]);
        *reinterpret_cast<float4*>(&xsh[node][q * 4]) = own;
    }
    if (tid < NPB) {
        int d = rp[blockBase + tid + 1] - rp[blockBase + tid];
        dsc[tid] = (d > 0) ? 1.0f / (float)d : 0.f;
    }
    __syncthreads();
    // --- edge streaming ---
    const int ebeg = rp[blockBase];
    const int eend = rp[blockBase + NPB];
    const int rowlane = tid & 15;          // 16 lanes cover one 64-float row
    const int up = (rowlane < 8);
    const int sub4 = (rowlane & 7) * 4;
    const int col0 = rowlane * 4;
    for (int e = ebeg + (tid >> 4); e < eend; e += 32) {
        const int2 p = colPair[e];
        const int loc = ((unsigned)p.x) >> 24;
        const int cc = up ? p.y : (p.x & 0xFFFFFF);
        const unsigned short* base = up ? xup : xlo;
        const float4 v = ldbf4(&base[(size_t)cc * 32 + sub4]);
        atomicAdd(&msh[loc][col0 + 0], v.x);
        atomicAdd(&msh[loc][col0 + 1], v.y);
        atomicAdd(&msh[loc][col0 + 2], v.z);
        atomicAdd(&msh[loc][col0 + 3], v.w);
    }
    __syncthreads();
    // --- scale sums -> means ---
    for (int idx = tid; idx < NPB * 16; idx += 512) {
        int node = idx >> 4, q = idx & 15;
        float sc = dsc[node];
        float4 v = *reinterpret_cast<float4*>(&msh[node][q * 4]);
        v.x *= sc; v.y *= sc; v.z *= sc; v.w *= sc;
        *reinterpret_cast<float4*>(&msh[node][q * 4]) = v;
    }
    __syncthreads();
    // --- phase B (unchanged) ---
    const int jq = lane % JQ;
    const int nd = lane / JQ;
    const float4 bv = *reinterpret_cast<const float4*>(&bias[jq * 4]);
    float4 acc[NSL];
#pragma unroll
    for (int sl = 0; sl < NSL; ++sl) acc[sl] = bv;
#pragma unroll 2
    for (int i = 0; i < DIN; i += 4) {
        const float4 w0 = *reinterpret_cast<const float4*>(&Ws[(i + 0) * DOUT + jq * 4]);
        const float4 w1 = *reinterpret_cast<const float4*>(&Ws[(i + 1) * DOUT + jq * 4]);
        const float4 w2 = *reinterpret_cast<const float4*>(&Ws[(i + 2) * DOUT + jq * 4]);
        const float4 w3 = *reinterpret_cast<const float4*>(&Ws[(i + 3) * DOUT + jq * 4]);
        const float4 u0 = *reinterpret_cast<const float4*>(&Wn[(i + 0) * DOUT + jq * 4]);
        const float4 u1 = *reinterpret_cast<const float4*>(&Wn[(i + 1) * DOUT + jq * 4]);
        const float4 u2 = *reinterpret_cast<const float4*>(&Wn[(i + 2) * DOUT + jq * 4]);
        const float4 u3 = *reinterpret_cast<const float4*>(&Wn[(i + 3) * DOUT + jq * 4]);
#pragma unroll
        for (int sl = 0; sl < NSL; ++sl) {
            const int kk = wave * NW + sl * NDP + nd;
            const float4 xv = *reinterpret_cast<const float4*>(&xsh[kk][i]);
            const float4 mv = *reinterpret_cast<const float4*>(&msh[kk][i]);
            fma4(acc[sl], xv.x, w0); fma4(acc[sl], xv.y, w1);
            fma4(acc[sl], xv.z, w2); fma4(acc[sl], xv.w, w3);
            fma4(acc[sl], mv.x, u0); fma4(acc[sl], mv.y, u1);
            fma4(acc[sl], mv.z, u2); fma4(acc[sl], mv.w, u3);
        }
    }
#pragma unroll
    for (int sl = 0; sl < NSL; ++sl) {
        const int kk = wave * NW + sl * NDP + nd;
        float4 o = make_float4(tanhf(acc[sl].x), tanhf(acc[sl].y),
                               tanhf(acc[sl].z), tanhf(acc[sl].w));
        stbf4(&h[(size_t)(blockBase + kk) * DOUT + jq * 4], o);
    }
}

// ===== pooling mean via CSR gather (bf16 in/out) =====

template<int F>
__global__ void csr_mean(const unsigned short* __restrict__ x, const int* __restrict__ rp,
                         const int* __restrict__ col, unsigned short* __restrict__ out, int n) {
    constexpr int G = 32, L4 = F / 4, EP = G / L4;
    int g = threadIdx.x / G, tg = threadIdx.x % G;
    int rowlane = tg % L4, esub = tg / L4;
    int seg = blockIdx.x * (256 / G) + g;
    if (seg >= n) return;
    int beg = rp[seg], end = rp[seg + 1];
    float4 s = make_float4(0.f, 0.f, 0.f, 0.f);
#pragma unroll 2
    for (int e = beg + esub; e < end; e += EP) {
        int c = col[e];
        const float4 v = ldbf4(&x[(size_t)c * F + rowlane * 4]);
        add4(s, v);
    }
#pragma unroll
    for (int m = L4; m < G; m <<= 1) red4(s, m);
    if (esub == 0) {
        float sc = (end > beg) ? 1.0f / (float)(end - beg) : 0.f;
        stbf4(&out[(size_t)seg * F + rowlane * 4],
              make_float4(s.x * sc, s.y * sc, s.z * sc, s.w * sc));
    }
}

// ===== fused conn-max + MLP (h0b bf16) =====

__global__ __launch_bounds__(512) void mlp_kernel(const unsigned short* __restrict__ h0b,
                           const int* __restrict__ rp, const int* __restrict__ col,
                           const float* __restrict__ xnet,
                           const float* __restrict__ w1, const float* __restrict__ b1,
                           const float* __restrict__ w2, const float* __restrict__ b2,
                           float* __restrict__ out) {
    constexpr int SD = 84;
    __shared__ float w1T[64 * SD];
    __shared__ float w2s[64];
    __shared__ float xin[8][SD];
    for (int idx = threadIdx.x; idx < 80 * 64; idx += 512) {
        int i = idx / 64, j = idx % 64;
        w1T[j * SD + i] = w1[idx];
    }
    if (threadIdx.x < 64) w2s[threadIdx.x] = w2[threadIdx.x];
    __syncthreads();
    int wv = threadIdx.x >> 6;
    int lane = threadIdx.x & 63;
    int rowlane = lane & 15, esub = lane >> 4;
    for (int r = 0; r < 4; ++r) {
        int net = blockIdx.x * 32 + r * 8 + wv;
        int beg = rp[net], end = rp[net + 1];
        float4 m = make_float4(-INFINITY, -INFINITY, -INFINITY, -INFINITY);
#pragma unroll 2
        for (int e = beg + esub; e < end; e += 4) {
            int c = col[e];
            const float4 v = ldbf4(&h0b[(size_t)c * 64 + rowlane * 4]);
            m.x = fmaxf(m.x, v.x); m.y = fmaxf(m.y, v.y);
            m.z = fmaxf(m.z, v.z); m.w = fmaxf(m.w, v.w);
        }
#pragma unroll
        for (int msk = 16; msk < 64; msk <<= 1) {
            m.x = fmaxf(m.x, __shfl_xor(m.x, msk, 64));
            m.y = fmaxf(m.y, __shfl_xor(m.y, msk, 64));
            m.z = fmaxf(m.z, __shfl_xor(m.z, msk, 64));
            m.w = fmaxf(m.w, __shfl_xor(m.w, msk, 64));
        }
        if (beg == end) m = make_float4(0.f, 0.f, 0.f, 0.f);
        if (esub == 0) *reinterpret_cast<float4*>(&xin[wv][rowlane * 4]) = m;
        else if (esub == 1) xin[wv][64 + rowlane] = xnet[(size_t)net * 16 + rowlane];
        float acc = b1[lane];
#pragma unroll
        for (int i = 0; i < 80; i += 4) {
            const float4 w4 = *reinterpret_cast<const float4*>(&w1T[lane * SD + i]);
            const float4 xv = *reinterpret_cast<const float4*>(&xin[wv][i]);
            acc += xv.x * w4.x + xv.y * w4.y + xv.z * w4.z + xv.w * w4.w;
        }
        float p = tanhf(acc) * w2s[lane];
#pragma unroll
        for (int off = 32; off > 0; off >>= 1) p += __shfl_down(p, off, 64);
        if (lane == 0) out[net] = p + b2[0];
    }
}

// ===== host =====

extern "C" void kernel_launch(void* const* d_in, const int* in_sizes, int n_in,
                              void* d_out, int out_size, void* d_ws, size_t ws_size,
                              hipStream_t stream) {
    (void)in_sizes; (void)n_in; (void)out_size; (void)ws_size;
    const float* x0   = (const float*)d_in[0];
    const float* xnet = (const float*)d_in[1];
    const float* Ws0 = (const float*)d_in[2];  const float* Wn0 = (const float*)d_in[3];  const float* b0 = (const float*)d_in[4];
    const float* Ws1 = (const float*)d_in[5];  const float* Wn1 = (const float*)d_in[6];  const float* b1 = (const float*)d_in[7];
    const float* Ws2 = (const float*)d_in[8];  const float* Wn2 = (const float*)d_in[9];  const float* b2 = (const float*)d_in[10];
    const float* Ws3 = (const float*)d_in[11]; const float* Wn3 = (const float*)d_in[12]; const float* b3 = (const float*)d_in[13];
    const float* Ws4 = (const float*)d_in[14]; const float* Wn4 = (const float*)d_in[15]; const float* b4 = (const float*)d_in[16];
    const float* mw1 = (const float*)d_in[17]; const float* mb1 = (const float*)d_in[18];
    const float* mw2 = (const float*)d_in[19]; const float* mb2 = (const float*)d_in[20];
    const int* e0s = (const int*)d_in[21]; const int* e0d = (const int*)d_in[22];
    const int* e1s = (const int*)d_in[23]; const int* e1d = (const int*)d_in[24];
    const int* e2s = (const int*)d_in[25]; const int* e2d = (const int*)d_in[26];
    const int* a01 = (const int*)d_in[27]; const int* a12 = (const int*)d_in[28];
    const int* cs  = (const int*)d_in[29]; const int* cd  = (const int*)d_in[30];

    char* ws = (char*)d_ws;
    const size_t MB = 1u << 20;
    int* rp0    = (int*)(ws + (size_t)(0.00 * MB));
    int* rp1    = (int*)(ws + (size_t)(1.25 * MB));
    int* rp2    = (int*)(ws + (size_t)(1.75 * MB));
    int* rpA01  = (int*)(ws + (size_t)(2.00 * MB));
    int* rpA12  = (int*)(ws + (size_t)(2.50 * MB));
    int* rpC    = (int*)(ws + (size_t)(2.75 * MB));
    int* bcnt   = (int*)(ws + (size_t)(3.75 * MB));
    int* bs     = (int*)(ws + (size_t)(3.75 * MB) + 4096);
    int* cur    = (int*)(ws + (size_t)(3.75 * MB) + 8192);
    int* colAll = (int*)(ws + (size_t)(4.00 * MB));         // 14.8MB -> ~18.8
    int2* colPair = (int2*)(ws + 19 * MB);                  // 21MB -> 40
    unsigned char* colLoc = (unsigned char*)(ws + 40 * MB); // 2.6MB -> ~42.7
    unsigned short* xb0 = (unsigned short*)(ws + 43 * MB);  // 8MB  -> 51
    unsigned short* h0  = (unsigned short*)(ws + 51 * MB);  // 16MB -> 67
    unsigned short* h1  = (unsigned short*)(ws + 67 * MB);  // 4MB  -> 71
    unsigned short* h2  = (unsigned short*)(ws + 71 * MB);  // 1MB  -> 72
    unsigned short* x1  = (unsigned short*)(ws + 72 * MB);  // 4MB  -> 76
    unsigned short* x2  = (unsigned short*)(ws + 76 * MB);  // 1MB  -> 77
    unsigned short* h1b = (unsigned short*)(ws + 77 * MB);  // 4MB  -> 81
    unsigned short* h0b = (unsigned short*)(ws + 81 * MB);  // 32MB -> 113
    int2* bin   = (int2*)(ws + 113 * MB);   // 31MB (build-only)

    // ---- binned CSR build ----
    hipMemsetAsync(bcnt, 0, NBK_TOT * 4, stream);
    bcount<<<dim3(CBT), 256, 0, stream>>>(e0d, e1d, e2d, a01, a12, cd, bcnt);
    bscan<<<dim3(1), 1024, 0, stream>>>(bcnt, bs, cur);
    bscatter<<<dim3(CBT), 256, 0, stream>>>(e0s, e0d, e1s, e1d, e2s, e2d, a01, a12, cs, cd,
                                            cur, bin);
    bbuild<<<dim3(NBK_TOT), 512, 0, stream>>>(bin, bs, colAll, colLoc,
                                              rp0, rp1, rp2, rpA01, rpA12, rpC);
    colpair_kernel<<<dim3((E0 + E1) / 256), 256, 0, stream>>>(colAll, colLoc, a01, a12, colPair);
    cvt_bf16<<<dim3(N0 * 16 / 4 / 256), 256, 0, stream>>>(x0, xb0, N0 * 16 / 4);

    // ---- layer 0: h0 = sage(x0, e0)  [N0,32] bf16
    sage_b<16, 32><<<dim3(N0 / 64), 512, 0, stream>>>(xb0, rp0, colAll, Ws0, Wn0, b0, h0, N0);
    // ---- pool 0->1: x1 = seg_mean(h0, assign01)  [N1,32] bf16
    csr_mean<32><<<dim3(N1 / 8), 256, 0, stream>>>(h0, rpA01, colAll, x1, N1);
    // ---- layer 1: h1 = sage(x1, e1)  [N1,32] bf16
    sage_b<32, 32><<<dim3(N1 / 64), 512, 0, stream>>>(x1, rp1, colAll, Ws1, Wn1, b1, h1, N1);
    // ---- pool 1->2: x2 = seg_mean(h1, assign12)  [N2,32] bf16
    csr_mean<32><<<dim3(N2 / 8), 256, 0, stream>>>(h1, rpA12, colAll, x2, N2);
    // ---- layer 2: h2 = sage(x2, e2)  [N2,32] bf16
    sage_b<32, 32><<<dim3(N2 / 64), 512, 0, stream>>>(x2, rp2, colAll, Ws2, Wn2, b2, h2, N2);
    // ---- up 2->1: h1b = sage([h2[a12[.]], h1], e1)  [N1,32] bf16, edge-streamed
    sage_cat<32><<<dim3(N1 / 64), 512, 0, stream>>>(h2, a12, h1, rp1, colPair,
                                                    Ws3, Wn3, b3, h1b, N1);
    // ---- up 1->0: h0b = sage([h1b[a01[.]], h0], e0)  [N0,64] bf16, edge-streamed
    sage_cat<64><<<dim3(N0 / 64), 512, 0, stream>>>(h1b, a01, h0, rp0, colPair,
                                                    Ws4, Wn4, b4, h0b, N0);
    // ---- fused per-net segment-max + MLP -> out [NNET,1]
    mlp_kernel<<<dim3(NNET / 32), 512, 0, stream>>>(h0b, rpC, colAll, xnet, mw1, mb1, mw2, mb2,
                                                    (float*)d_out);
}

// Round 18
// 670.176 us; speedup vs baseline: 1.9822x; 1.9822x over previous
//
#include <hip/hip_runtime.h>

#define N0 262144
#define N1 65536
#define N2 16384
#define NNET 200000
#define E0 2097152
#define E1 524288
#define E2 131072
#define ECONN 800000

// ===== binned CSR build =====
#define BSH 10
#define NBK_TOT 612
#define CHK 16384
#define CBT 237

__global__ void bcount(const int* __restrict__ e0d, const int* __restrict__ e1d,
                       const int* __restrict__ e2d, const int* __restrict__ a01,
                       const int* __restrict__ a12, const int* __restrict__ cd,
                       int* __restrict__ bcnt) {
    int bb = blockIdx.x; int lb, nE, nbuk, gb; const int* dst;
    if (bb < 128)      { lb=bb;     dst=e0d; nE=E0;    nbuk=256; gb=0; }
    else if (bb < 160) { lb=bb-128; dst=e1d; nE=E1;    nbuk=64;  gb=256; }
    else if (bb < 168) { lb=bb-160; dst=e2d; nE=E2;    nbuk=16;  gb=320; }
    else if (bb < 184) { lb=bb-168; dst=a01; nE=N0;    nbuk=64;  gb=336; }
    else if (bb < 188) { lb=bb-184; dst=a12; nE=N1;    nbuk=16;  gb=400; }
    else               { lb=bb-188; dst=cd;  nE=ECONN; nbuk=196; gb=416; }
    __shared__ int h[256];
    for (int i = threadIdx.x; i < nbuk; i += 256) h[i] = 0;
    __syncthreads();
    int base = lb * CHK;
    for (int k = 0; k < CHK / 256; ++k) {
        int e = base + k * 256 + threadIdx.x;
        if (e < nE) atomicAdd(&h[dst[e] >> BSH], 1);
    }
    __syncthreads();
    for (int i = threadIdx.x; i < nbuk; i += 256)
        if (h[i]) atomicAdd(&bcnt[gb + i], h[i]);
}

__global__ __launch_bounds__(1024) void bscan(const int* __restrict__ bcnt,
                                              int* __restrict__ bs, int* __restrict__ cur) {
    __shared__ int ts[1024];
    int t = threadIdx.x;
    int v = (t < NBK_TOT) ? bcnt[t] : 0;
    ts[t] = v; __syncthreads();
    for (int off = 1; off < 1024; off <<= 1) {
        int u = (t >= off) ? ts[t - off] : 0; __syncthreads();
        ts[t] += u; __syncthreads();
    }
    if (t < NBK_TOT) {
        int ex = ts[t] - v;
        bs[t] = ex; cur[t] = ex;
        if (t == NBK_TOT - 1) bs[NBK_TOT] = ts[t];
    }
}

__global__ void bscatter(const int* e0s, const int* e0d, const int* e1s, const int* e1d,
                         const int* e2s, const int* e2d, const int* a01, const int* a12,
                         const int* cs, const int* cd,
                         int* __restrict__ cur, int2* __restrict__ bin) {
    int bb = blockIdx.x; int lb, nE, nbuk, gb; const int* dst; const int* src;
    if (bb < 128)      { lb=bb;     dst=e0d; src=e0s;     nE=E0;    nbuk=256; gb=0; }
    else if (bb < 160) { lb=bb-128; dst=e1d; src=e1s;     nE=E1;    nbuk=64;  gb=256; }
    else if (bb < 168) { lb=bb-160; dst=e2d; src=e2s;     nE=E2;    nbuk=16;  gb=320; }
    else if (bb < 184) { lb=bb-168; dst=a01; src=nullptr; nE=N0;    nbuk=64;  gb=336; }
    else if (bb < 188) { lb=bb-184; dst=a12; src=nullptr; nE=N1;    nbuk=16;  gb=400; }
    else               { lb=bb-188; dst=cd;  src=cs;      nE=ECONN; nbuk=196; gb=416; }
    __shared__ int h[256];
    __shared__ int curl[256];
    for (int i = threadIdx.x; i < nbuk; i += 256) h[i] = 0;
    __syncthreads();
    int base = lb * CHK;
    for (int k = 0; k < CHK / 256; ++k) {
        int e = base + k * 256 + threadIdx.x;
        if (e < nE) atomicAdd(&h[dst[e] >> BSH], 1);
    }
    __syncthreads();
    for (int i = threadIdx.x; i < nbuk; i += 256)
        if (h[i]) curl[i] = atomicAdd(&cur[gb + i], h[i]);
    __syncthreads();
    for (int k = 0; k < CHK / 256; ++k) {
        int e = base + k * 256 + threadIdx.x;
        if (e < nE) {
            int d = dst[e];
            int pos = atomicAdd(&curl[d >> BSH], 1);
            bin[pos] = make_int2(d, src ? src[e] : e);
        }
    }
}

__global__ __launch_bounds__(512) void bbuild(const int2* __restrict__ bin,
                        const int* __restrict__ bs, int* __restrict__ colAll,
                        int* rp0, int* rp1, int* rp2, int* rpA01, int* rpA12, int* rpC) {
    int g = blockIdx.x; int lb, nSeg, last; int* rp;
    if (g < 256)      { lb=g;     nSeg=N0;   rp=rp0;   last=(g==255); }
    else if (g < 320) { lb=g-256; nSeg=N1;   rp=rp1;   last=(g==319); }
    else if (g < 336) { lb=g-320; nSeg=N2;   rp=rp2;   last=(g==335); }
    else if (g < 400) { lb=g-336; nSeg=N1;   rp=rpA01; last=(g==399); }
    else if (g < 416) { lb=g-400; nSeg=N2;   rp=rpA12; last=(g==415); }
    else              { lb=g-416; nSeg=NNET; rp=rpC;   last=(g==611); }
    const int nodeBase = lb << BSH;
    const int begE = bs[g], endE = bs[g + 1];
    __shared__ int cnt[1024];
    __shared__ int rpl[1024];
    __shared__ int ts[512];
    const int t = threadIdx.x;
    cnt[t] = 0; cnt[t + 512] = 0;
    __syncthreads();
    for (int e = begE + t; e < endE; e += 512)
        atomicAdd(&cnt[bin[e].x - nodeBase], 1);
    __syncthreads();
    int a = cnt[2 * t], b = cnt[2 * t + 1];
    int s = a + b;
    ts[t] = s; __syncthreads();
    for (int off = 1; off < 512; off <<= 1) {
        int u = (t >= off) ? ts[t - off] : 0; __syncthreads();
        ts[t] += u; __syncthreads();
    }
    int pre = ts[t] - s;
    rpl[2 * t] = pre; rpl[2 * t + 1] = pre + a;
    __syncthreads();
    int lim = nSeg - nodeBase; if (lim > 1024) lim = 1024;
    for (int i = t; i < lim; i += 512) {
        int abs0 = begE + rpl[i];
        rp[nodeBase + i] = abs0;
        cnt[i] = abs0;
    }
    if (last && t == 0) rp[nSeg] = endE;
    __syncthreads();
    for (int e = begE + t; e < endE; e += 512) {
        int2 p = bin[e];
        int pos = atomicAdd(&cnt[p.x - nodeBase], 1);
        colAll[pos] = p.y;
    }
}

// ===== colPair: (col, asgn[col]) per e0/e1 CSR slot =====
__global__ void colpair_kernel(const int* __restrict__ colAll,
                               const int* __restrict__ a01, const int* __restrict__ a12,
                               int2* __restrict__ colPair) {
    int i = blockIdx.x * blockDim.x + threadIdx.x;   // grid covers exactly E0+E1
    int c = colAll[i];
    int up = (i < E0) ? a01[c] : a12[c];
    colPair[i] = make_int2(c, up);
}

// ===== helpers =====
__device__ __forceinline__ unsigned short f2bf(float f) {   // RNE pack
    unsigned u = __float_as_uint(f);
    u += 0x7FFFu + ((u >> 16) & 1u);
    return (unsigned short)(u >> 16);
}
__device__ __forceinline__ float bf2f(unsigned short s) {
    return __uint_as_float((unsigned)s << 16);
}
__device__ __forceinline__ float4 ldbf4(const unsigned short* p) {
    ushort4 u = *reinterpret_cast<const ushort4*>(p);
    return make_float4(bf2f(u.x), bf2f(u.y), bf2f(u.z), bf2f(u.w));
}
__device__ __forceinline__ void stbf4(unsigned short* p, const float4& v) {
    ushort4 u; u.x = f2bf(v.x); u.y = f2bf(v.y); u.z = f2bf(v.z); u.w = f2bf(v.w);
    *reinterpret_cast<ushort4*>(p) = u;
}
__device__ __forceinline__ void fma4(float4& a, float s, const float4& b) {
    a.x = fmaf(s, b.x, a.x); a.y = fmaf(s, b.y, a.y);
    a.z = fmaf(s, b.z, a.z); a.w = fmaf(s, b.w, a.w);
}
__device__ __forceinline__ void red4(float4& s, int m) {
    s.x += __shfl_xor(s.x, m, 64);
    s.y += __shfl_xor(s.y, m, 64);
    s.z += __shfl_xor(s.z, m, 64);
    s.w += __shfl_xor(s.w, m, 64);
}
__device__ __forceinline__ void add4(float4& a, const float4& b) {
    a.x += b.x; a.y += b.y; a.z += b.z; a.w += b.w;
}

// ===== fp32 -> bf16 streaming convert (x0 -> xb0) =====
__global__ void cvt_bf16(const float* __restrict__ in, unsigned short* __restrict__ out, int n4) {
    int i = blockIdx.x * blockDim.x + threadIdx.x;
    if (i < n4) {
        float4 v = reinterpret_cast<const float4*>(in)[i];
        stbf4(&out[(size_t)i * 4], v);
    }
}

// ===== fused SAGE, barrier-free; bf16 features in/out, fp32 accumulate =====

template<int DIN, int DOUT>
__global__ __launch_bounds__(512) void sage_b(const unsigned short* __restrict__ x,
                       const int* __restrict__ rp, const int* __restrict__ col,
                       const float* __restrict__ Ws, const float* __restrict__ Wn,
                       const float* __restrict__ bias, unsigned short* __restrict__ h, int n) {
    constexpr int NW  = 8;
    constexpr int NPB = 64;
    constexpr int L4  = DIN / 4;
    constexpr int EPA = 64 / L4;
    constexpr int SD  = DIN + 4;
    constexpr int JQ  = DOUT / 4;
    constexpr int NDP = 64 / JQ;
    constexpr int NSL = NW / NDP;
    __shared__ float xsh[NPB][SD];
    __shared__ float msh[NPB][SD];
    const int wave = threadIdx.x >> 6;
    const int lane = threadIdx.x & 63;
    const int rowlane = lane % L4;
    const int esub = lane / L4;
    const int blockBase = blockIdx.x * NPB;
#pragma unroll
    for (int k = 0; k < NW; ++k) {
        const int kk = wave * NW + k;
        const int node = blockBase + kk;
        const int beg = rp[node], end = rp[node + 1];
        float4 own = make_float4(0.f, 0.f, 0.f, 0.f);
        if (lane < L4) own = ldbf4(&x[(size_t)node * DIN + lane * 4]);
        float4 s = make_float4(0.f, 0.f, 0.f, 0.f);
#pragma unroll 2
        for (int e = beg + esub; e < end; e += EPA) {
            const int c = col[e];
            const float4 v = ldbf4(&x[(size_t)c * DIN + rowlane * 4]);
            add4(s, v);
        }
#pragma unroll
        for (int m = L4; m < 64; m <<= 1) red4(s, m);
        if (lane < L4) {
            float sc = (end > beg) ? 1.0f / (float)(end - beg) : 0.f;
            *reinterpret_cast<float4*>(&msh[kk][lane * 4]) =
                make_float4(s.x * sc, s.y * sc, s.z * sc, s.w * sc);
            *reinterpret_cast<float4*>(&xsh[kk][lane * 4]) = own;
        }
    }
    asm volatile("s_waitcnt lgkmcnt(0)" ::: "memory");
    __builtin_amdgcn_wave_barrier();
    const int jq = lane % JQ;
    const int nd = lane / JQ;
    const float4 bv = *reinterpret_cast<const float4*>(&bias[jq * 4]);
    float4 acc[NSL];
#pragma unroll
    for (int sl = 0; sl < NSL; ++sl) acc[sl] = bv;
#pragma unroll 2
    for (int i = 0; i < DIN; i += 4) {
        const float4 w0 = *reinterpret_cast<const float4*>(&Ws[(i + 0) * DOUT + jq * 4]);
        const float4 w1 = *reinterpret_cast<const float4*>(&Ws[(i + 1) * DOUT + jq * 4]);
        const float4 w2 = *reinterpret_cast<const float4*>(&Ws[(i + 2) * DOUT + jq * 4]);
        const float4 w3 = *reinterpret_cast<const float4*>(&Ws[(i + 3) * DOUT + jq * 4]);
        const float4 u0 = *reinterpret_cast<const float4*>(&Wn[(i + 0) * DOUT + jq * 4]);
        const float4 u1 = *reinterpret_cast<const float4*>(&Wn[(i + 1) * DOUT + jq * 4]);
        const float4 u2 = *reinterpret_cast<const float4*>(&Wn[(i + 2) * DOUT + jq * 4]);
        const float4 u3 = *reinterpret_cast<const float4*>(&Wn[(i + 3) * DOUT + jq * 4]);
#pragma unroll
        for (int sl = 0; sl < NSL; ++sl) {
            const int kk = wave * NW + sl * NDP + nd;
            const float4 xv = *reinterpret_cast<const float4*>(&xsh[kk][i]);
            const float4 mv = *reinterpret_cast<const float4*>(&msh[kk][i]);
            fma4(acc[sl], xv.x, w0); fma4(acc[sl], xv.y, w1);
            fma4(acc[sl], xv.z, w2); fma4(acc[sl], xv.w, w3);
            fma4(acc[sl], mv.x, u0); fma4(acc[sl], mv.y, u1);
            fma4(acc[sl], mv.z, u2); fma4(acc[sl], mv.w, u3);
        }
    }
#pragma unroll
    for (int sl = 0; sl < NSL; ++sl) {
        const int kk = wave * NW + sl * NDP + nd;
        float4 o = make_float4(tanhf(acc[sl].x), tanhf(acc[sl].y),
                               tanhf(acc[sl].z), tanhf(acc[sl].w));
        stbf4(&h[(size_t)(blockBase + kk) * DOUT + jq * 4], o);
    }
}

// ===== fused concat+SAGE for up-layers (node-major, colPair); bf16 in/out =====

template<int DOUT>
__global__ __launch_bounds__(512) void sage_cat(const unsigned short* __restrict__ xup,
                       const int* __restrict__ asgn, const unsigned short* __restrict__ xlo,
                       const int* __restrict__ rp, const int2* __restrict__ colPair,
                       const float* __restrict__ Ws, const float* __restrict__ Wn,
                       const float* __restrict__ bias, unsigned short* __restrict__ h, int n) {
    constexpr int DIN = 64;
    constexpr int NW  = 8;
    constexpr int NPB = 64;
    constexpr int L4  = 16;
    constexpr int EPA = 4;
    constexpr int SD  = DIN + 4;
    constexpr int JQ  = DOUT / 4;
    constexpr int NDP = 64 / JQ;
    constexpr int NSL = NW / NDP;
    __shared__ float xsh[NPB][SD];
    __shared__ float msh[NPB][SD];
    const int wave = threadIdx.x >> 6;
    const int lane = threadIdx.x & 63;
    const int rowlane = lane % L4;
    const int esub = lane / L4;
    const int up = (rowlane < 8);
    const int sub4 = (rowlane & 7) * 4;
    const int blockBase = blockIdx.x * NPB;
#pragma unroll
    for (int k = 0; k < NW; ++k) {
        const int kk = wave * NW + k;
        const int node = blockBase + kk;
        const int beg = rp[node], end = rp[node + 1];
        const unsigned short* base = up ? xup : xlo;
        float4 own = make_float4(0.f, 0.f, 0.f, 0.f);
        if (lane < L4) {
            int cc = up ? asgn[node] : node;
            own = ldbf4(&base[(size_t)cc * 32 + sub4]);
        }
        float4 s = make_float4(0.f, 0.f, 0.f, 0.f);
#pragma unroll 2
        for (int e = beg + esub; e < end; e += EPA) {
            const int2 p = colPair[e];
            const int cc = up ? p.y : p.x;
            const float4 v = ldbf4(&base[(size_t)cc * 32 + sub4]);
            add4(s, v);
        }
#pragma unroll
        for (int m = L4; m < 64; m <<= 1) red4(s, m);
        if (lane < L4) {
            float sc = (end > beg) ? 1.0f / (float)(end - beg) : 0.f;
            *reinterpret_cast<float4*>(&msh[kk][lane * 4]) =
                make_float4(s.x * sc, s.y * sc, s.z * sc, s.w * sc);
            *reinterpret_cast<float4*>(&xsh[kk][lane * 4]) = own;
        }
    }
    asm volatile("s_waitcnt lgkmcnt(0)" ::: "memory");
    __builtin_amdgcn_wave_barrier();
    const int jq = lane % JQ;
    const int nd = lane / JQ;
    const float4 bv = *reinterpret_cast<const float4*>(&bias[jq * 4]);
    float4 acc[NSL];
#pragma unroll
    for (int sl = 0; sl < NSL; ++sl) acc[sl] = bv;
#pragma unroll 2
    for (int i = 0; i < DIN; i += 4) {
        const float4 w0 = *reinterpret_cast<const float4*>(&Ws[(i + 0) * DOUT + jq * 4]);
        const float4 w1 = *reinterpret_cast<const float4*>(&Ws[(i + 1) * DOUT + jq * 4]);
        const float4 w2 = *reinterpret_cast<const float4*>(&Ws[(i + 2) * DOUT + jq * 4]);
        const float4 w3 = *reinterpret_cast<const float4*>(&Ws[(i + 3) * DOUT + jq * 4]);
        const float4 u0 = *reinterpret_cast<const float4*>(&Wn[(i + 0) * DOUT + jq * 4]);
        const float4 u1 = *reinterpret_cast<const float4*>(&Wn[(i + 1) * DOUT + jq * 4]);
        const float4 u2 = *reinterpret_cast<const float4*>(&Wn[(i + 2) * DOUT + jq * 4]);
        const float4 u3 = *reinterpret_cast<const float4*>(&Wn[(i + 3) * DOUT + jq * 4]);
#pragma unroll
        for (int sl = 0; sl < NSL; ++sl) {
            const int kk = wave * NW + sl * NDP + nd;
            const float4 xv = *reinterpret_cast<const float4*>(&xsh[kk][i]);
            const float4 mv = *reinterpret_cast<const float4*>(&msh[kk][i]);
            fma4(acc[sl], xv.x, w0); fma4(acc[sl], xv.y, w1);
            fma4(acc[sl], xv.z, w2); fma4(acc[sl], xv.w, w3);
            fma4(acc[sl], mv.x, u0); fma4(acc[sl], mv.y, u1);
            fma4(acc[sl], mv.z, u2); fma4(acc[sl], mv.w, u3);
        }
    }
#pragma unroll
    for (int sl = 0; sl < NSL; ++sl) {
        const int kk = wave * NW + sl * NDP + nd;
        float4 o = make_float4(tanhf(acc[sl].x), tanhf(acc[sl].y),
                               tanhf(acc[sl].z), tanhf(acc[sl].w));
        stbf4(&h[(size_t)(blockBase + kk) * DOUT + jq * 4], o);
    }
}

// ===== pooling mean via CSR gather (bf16 in/out) =====

template<int F>
__global__ void csr_mean(const unsigned short* __restrict__ x, const int* __restrict__ rp,
                         const int* __restrict__ col, unsigned short* __restrict__ out, int n) {
    constexpr int G = 32, L4 = F / 4, EP = G / L4;
    int g = threadIdx.x / G, tg = threadIdx.x % G;
    int rowlane = tg % L4, esub = tg / L4;
    int seg = blockIdx.x * (256 / G) + g;
    if (seg >= n) return;
    int beg = rp[seg], end = rp[seg + 1];
    float4 s = make_float4(0.f, 0.f, 0.f, 0.f);
#pragma unroll 2
    for (int e = beg + esub; e < end; e += EP) {
        int c = col[e];
        const float4 v = ldbf4(&x[(size_t)c * F + rowlane * 4]);
        add4(s, v);
    }
#pragma unroll
    for (int m = L4; m < G; m <<= 1) red4(s, m);
    if (esub == 0) {
        float sc = (end > beg) ? 1.0f / (float)(end - beg) : 0.f;
        stbf4(&out[(size_t)seg * F + rowlane * 4],
              make_float4(s.x * sc, s.y * sc, s.z * sc, s.w * sc));
    }
}

// ===== fused conn-max + MLP (h0b bf16) =====

__global__ __launch_bounds__(512) void mlp_kernel(const unsigned short* __restrict__ h0b,
                           const int* __restrict__ rp, const int* __restrict__ col,
                           const float* __restrict__ xnet,
                           const float* __restrict__ w1, const float* __restrict__ b1,
                           const float* __restrict__ w2, const float* __restrict__ b2,
                           float* __restrict__ out) {
    constexpr int SD = 84;
    __shared__ float w1T[64 * SD];
    __shared__ float w2s[64];
    __shared__ float xin[8][SD];
    for (int idx = threadIdx.x; idx < 80 * 64; idx += 512) {
        int i = idx / 64, j = idx % 64;
        w1T[j * SD + i] = w1[idx];
    }
    if (threadIdx.x < 64) w2s[threadIdx.x] = w2[threadIdx.x];
    __syncthreads();
    int wv = threadIdx.x >> 6;
    int lane = threadIdx.x & 63;
    int rowlane = lane & 15, esub = lane >> 4;
    for (int r = 0; r < 4; ++r) {
        int net = blockIdx.x * 32 + r * 8 + wv;
        int beg = rp[net], end = rp[net + 1];
        float4 m = make_float4(-INFINITY, -INFINITY, -INFINITY, -INFINITY);
#pragma unroll 2
        for (int e = beg + esub; e < end; e += 4) {
            int c = col[e];
            const float4 v = ldbf4(&h0b[(size_t)c * 64 + rowlane * 4]);
            m.x = fmaxf(m.x, v.x); m.y = fmaxf(m.y, v.y);
            m.z = fmaxf(m.z, v.z); m.w = fmaxf(m.w, v.w);
        }
#pragma unroll
        for (int msk = 16; msk < 64; msk <<= 1) {
            m.x = fmaxf(m.x, __shfl_xor(m.x, msk, 64));
            m.y = fmaxf(m.y, __shfl_xor(m.y, msk, 64));
            m.z = fmaxf(m.z, __shfl_xor(m.z, msk, 64));
            m.w = fmaxf(m.w, __shfl_xor(m.w, msk, 64));
        }
        if (beg == end) m = make_float4(0.f, 0.f, 0.f, 0.f);
        if (esub == 0) *reinterpret_cast<float4*>(&xin[wv][rowlane * 4]) = m;
        else if (esub == 1) xin[wv][64 + rowlane] = xnet[(size_t)net * 16 + rowlane];
        float acc = b1[lane];
#pragma unroll
        for (int i = 0; i < 80; i += 4) {
            const float4 w4 = *reinterpret_cast<const float4*>(&w1T[lane * SD + i]);
            const float4 xv = *reinterpret_cast<const float4*>(&xin[wv][i]);
            acc += xv.x * w4.x + xv.y * w4.y + xv.z * w4.z + xv.w * w4.w;
        }
        float p = tanhf(acc) * w2s[lane];
#pragma unroll
        for (int off = 32; off > 0; off >>= 1) p += __shfl_down(p, off, 64);
        if (lane == 0) out[net] = p + b2[0];
    }
}

// ===== host =====

extern "C" void kernel_launch(void* const* d_in, const int* in_sizes, int n_in,
                              void* d_out, int out_size, void* d_ws, size_t ws_size,
                              hipStream_t stream) {
    (void)in_sizes; (void)n_in; (void)out_size; (void)ws_size;
    const float* x0   = (const float*)d_in[0];
    const float* xnet = (const float*)d_in[1];
    const float* Ws0 = (const float*)d_in[2];  const float* Wn0 = (const float*)d_in[3];  const float* b0 = (const float*)d_in[4];
    const float* Ws1 = (const float*)d_in[5];  const float* Wn1 = (const float*)d_in[6];  const float* b1 = (const float*)d_in[7];
    const float* Ws2 = (const float*)d_in[8];  const float* Wn2 = (const float*)d_in[9];  const float* b2 = (const float*)d_in[10];
    const float* Ws3 = (const float*)d_in[11]; const float* Wn3 = (const float*)d_in[12]; const float* b3 = (const float*)d_in[13];
    const float* Ws4 = (const float*)d_in[14]; const float* Wn4 = (const float*)d_in[15]; const float* b4 = (const float*)d_in[16];
    const float* mw1 = (const float*)d_in[17]; const float* mb1 = (const float*)d_in[18];
    const float* mw2 = (const float*)d_in[19]; const float* mb2 = (const float*)d_in[20];
    const int* e0s = (const int*)d_in[21]; const int* e0d = (const int*)d_in[22];
    const int* e1s = (const int*)d_in[23]; const int* e1d = (const int*)d_in[24];
    const int* e2s = (const int*)d_in[25]; const int* e2d = (const int*)d_in[26];
    const int* a01 = (const int*)d_in[27]; const int* a12 = (const int*)d_in[28];
    const int* cs  = (const int*)d_in[29]; const int* cd  = (const int*)d_in[30];

    char* ws = (char*)d_ws;
    const size_t MB = 1u << 20;
    int* rp0    = (int*)(ws + (size_t)(0.00 * MB));
    int* rp1    = (int*)(ws + (size_t)(1.25 * MB));
    int* rp2    = (int*)(ws + (size_t)(1.75 * MB));
    int* rpA01  = (int*)(ws + (size_t)(2.00 * MB));
    int* rpA12  = (int*)(ws + (size_t)(2.50 * MB));
    int* rpC    = (int*)(ws + (size_t)(2.75 * MB));
    int* bcnt   = (int*)(ws + (size_t)(3.75 * MB));
    int* bs     = (int*)(ws + (size_t)(3.75 * MB) + 4096);
    int* cur    = (int*)(ws + (size_t)(3.75 * MB) + 8192);
    int* colAll = (int*)(ws + (size_t)(4.00 * MB));     // 14.8MB -> ends ~18.8
    int2* colPair = (int2*)(ws + 19 * MB);              // 21MB -> 40
    unsigned short* xb0 = (unsigned short*)(ws + 41 * MB);  // N0*16 bf16 = 8MB  -> 49
    unsigned short* h0  = (unsigned short*)(ws + 49 * MB);  // N0*32 bf16 = 16MB -> 65
    unsigned short* h1  = (unsigned short*)(ws + 65 * MB);  // 4MB  -> 69
    unsigned short* h2  = (unsigned short*)(ws + 69 * MB);  // 1MB  -> 70
    unsigned short* x1  = (unsigned short*)(ws + 70 * MB);  // 4MB  -> 74
    unsigned short* x2  = (unsigned short*)(ws + 74 * MB);  // 1MB  -> 75
    unsigned short* h1b = (unsigned short*)(ws + 75 * MB);  // 4MB  -> 79
    unsigned short* h0b = (unsigned short*)(ws + 79 * MB);  // N0*64 bf16 = 32MB -> 111
    int2* bin   = (int2*)(ws + 111 * MB);   // 31MB (build-only, dead before h arrays used)

    // ---- binned CSR build ----
    hipMemsetAsync(bcnt, 0, NBK_TOT * 4, stream);
    bcount<<<dim3(CBT), 256, 0, stream>>>(e0d, e1d, e2d, a01, a12, cd, bcnt);
    bscan<<<dim3(1), 1024, 0, stream>>>(bcnt, bs, cur);
    bscatter<<<dim3(CBT), 256, 0, stream>>>(e0s, e0d, e1s, e1d, e2s, e2d, a01, a12, cs, cd,
                                            cur, bin);
    bbuild<<<dim3(NBK_TOT), 512, 0, stream>>>(bin, bs, colAll,
                                              rp0, rp1, rp2, rpA01, rpA12, rpC);
    colpair_kernel<<<dim3((E0 + E1) / 256), 256, 0, stream>>>(colAll, a01, a12, colPair);
    // x0 -> bf16 copy (gather working set 16MB -> 8MB)
    cvt_bf16<<<dim3(N0 * 16 / 4 / 256), 256, 0, stream>>>(x0, xb0, N0 * 16 / 4);

    // ---- layer 0: h0 = sage(x0, e0)  [N0,32] bf16
    sage_b<16, 32><<<dim3(N0 / 64), 512, 0, stream>>>(xb0, rp0, colAll, Ws0, Wn0, b0, h0, N0);
    // ---- pool 0->1: x1 = seg_mean(h0, assign01)  [N1,32] bf16
    csr_mean<32><<<dim3(N1 / 8), 256, 0, stream>>>(h0, rpA01, colAll, x1, N1);
    // ---- layer 1: h1 = sage(x1, e1)  [N1,32] bf16
    sage_b<32, 32><<<dim3(N1 / 64), 512, 0, stream>>>(x1, rp1, colAll, Ws1, Wn1, b1, h1, N1);
    // ---- pool 1->2: x2 = seg_mean(h1, assign12)  [N2,32] bf16
    csr_mean<32><<<dim3(N2 / 8), 256, 0, stream>>>(h1, rpA12, colAll, x2, N2);
    // ---- layer 2: h2 = sage(x2, e2)  [N2,32] bf16
    sage_b<32, 32><<<dim3(N2 / 64), 512, 0, stream>>>(x2, rp2, colAll, Ws2, Wn2, b2, h2, N2);
    // ---- up 2->1: h1b = sage([h2[a12[.]], h1], e1)  [N1,32] bf16
    sage_cat<32><<<dim3(N1 / 64), 512, 0, stream>>>(h2, a12, h1, rp1, colPair,
                                                    Ws3, Wn3, b3, h1b, N1);
    // ---- up 1->0: h0b = sage([h1b[a01[.]], h0], e0)  [N0,64] bf16
    sage_cat<64><<<dim3(N0 / 64), 512, 0, stream>>>(h1b, a01, h0, rp0, colPair,
                                                    Ws4, Wn4, b4, h0b, N0);
    // ---- fused per-net segment-max + MLP -> out [NNET,1]
    mlp_kernel<<<dim3(NNET / 32), 512, 0, stream>>>(h0b, rpC, colAll, xnet, mw1, mb1, mw2, mb2,
                                                    (float*)d_out);
}

// Round 19
// 655.983 us; speedup vs baseline: 2.0251x; 1.0216x over previous
//
#include <hip/hip_runtime.h>

#define N0 262144
#define N1 65536
#define N2 16384
#define NNET 200000
#define E0 2097152
#define E1 524288
#define E2 131072
#define ECONN 800000

// ===== binned CSR build (padded-bin: no bcount pass) =====
#define BSH 10
#define NBK_TOT 612
#define CHK 16384
#define CBT 237
#define CAP_BIN 10240   // per-bucket bin capacity; e0 buckets: mean 8192, sigma~90 -> 22 sigma margin

__global__ void bscatter(const int* e0s, const int* e0d, const int* e1s, const int* e1d,
                         const int* e2s, const int* e2d, const int* a01, const int* a12,
                         const int* cs, const int* cd,
                         int* __restrict__ cntg, int2* __restrict__ bin) {
    int bb = blockIdx.x; int lb, nE, nbuk, gb; const int* dst; const int* src;
    if (bb < 128)      { lb=bb;     dst=e0d; src=e0s;     nE=E0;    nbuk=256; gb=0; }
    else if (bb < 160) { lb=bb-128; dst=e1d; src=e1s;     nE=E1;    nbuk=64;  gb=256; }
    else if (bb < 168) { lb=bb-160; dst=e2d; src=e2s;     nE=E2;    nbuk=16;  gb=320; }
    else if (bb < 184) { lb=bb-168; dst=a01; src=nullptr; nE=N0;    nbuk=64;  gb=336; }
    else if (bb < 188) { lb=bb-184; dst=a12; src=nullptr; nE=N1;    nbuk=16;  gb=400; }
    else               { lb=bb-188; dst=cd;  src=cs;      nE=ECONN; nbuk=196; gb=416; }
    __shared__ int h[256];
    __shared__ int curl[256];
    for (int i = threadIdx.x; i < nbuk; i += 256) h[i] = 0;
    __syncthreads();
    int base = lb * CHK;
    for (int k = 0; k < CHK / 256; ++k) {
        int e = base + k * 256 + threadIdx.x;
        if (e < nE) atomicAdd(&h[dst[e] >> BSH], 1);
    }
    __syncthreads();
    for (int i = threadIdx.x; i < nbuk; i += 256)
        if (h[i]) curl[i] = (gb + i) * CAP_BIN + atomicAdd(&cntg[gb + i], h[i]);
    __syncthreads();
    for (int k = 0; k < CHK / 256; ++k) {
        int e = base + k * 256 + threadIdx.x;
        if (e < nE) {
            int d = dst[e];
            int pos = atomicAdd(&curl[d >> BSH], 1);
            bin[pos] = make_int2(d, src ? src[e] : e);
        }
    }
}

// scan post-scatter bucket counts -> dense output bases bs[0..NBK_TOT]
__global__ __launch_bounds__(1024) void bscan(const int* __restrict__ cntg,
                                              int* __restrict__ bs) {
    __shared__ int ts[1024];
    int t = threadIdx.x;
    int v = (t < NBK_TOT) ? cntg[t] : 0;
    ts[t] = v; __syncthreads();
    for (int off = 1; off < 1024; off <<= 1) {
        int u = (t >= off) ? ts[t - off] : 0; __syncthreads();
        ts[t] += u; __syncthreads();
    }
    if (t < NBK_TOT) {
        bs[t] = ts[t] - v;
        if (t == NBK_TOT - 1) bs[NBK_TOT] = ts[t];
    }
}

// bbuild: input = padded bin window [g*CAP_BIN, g*CAP_BIN + m); output dense.
__global__ __launch_bounds__(512) void bbuild(const int2* __restrict__ bin,
                        const int* __restrict__ bs, int* __restrict__ colAll,
                        int* rp0, int* rp1, int* rp2, int* rpA01, int* rpA12, int* rpC) {
    int g = blockIdx.x; int lb, nSeg, last; int* rp;
    if (g < 256)      { lb=g;     nSeg=N0;   rp=rp0;   last=(g==255); }
    else if (g < 320) { lb=g-256; nSeg=N1;   rp=rp1;   last=(g==319); }
    else if (g < 336) { lb=g-320; nSeg=N2;   rp=rp2;   last=(g==335); }
    else if (g < 400) { lb=g-336; nSeg=N1;   rp=rpA01; last=(g==399); }
    else if (g < 416) { lb=g-400; nSeg=N2;   rp=rpA12; last=(g==415); }
    else              { lb=g-416; nSeg=NNET; rp=rpC;   last=(g==611); }
    const int nodeBase = lb << BSH;
    const int outBeg = bs[g], outEnd = bs[g + 1];
    const int m = outEnd - outBeg;
    const int inBeg = g * CAP_BIN;
    __shared__ int cnt[1024];
    __shared__ int rpl[1024];
    __shared__ int ts[512];
    const int t = threadIdx.x;
    cnt[t] = 0; cnt[t + 512] = 0;
    __syncthreads();
    for (int e = inBeg + t; e < inBeg + m; e += 512)
        atomicAdd(&cnt[bin[e].x - nodeBase], 1);
    __syncthreads();
    int a = cnt[2 * t], b = cnt[2 * t + 1];
    int s = a + b;
    ts[t] = s; __syncthreads();
    for (int off = 1; off < 512; off <<= 1) {
        int u = (t >= off) ? ts[t - off] : 0; __syncthreads();
        ts[t] += u; __syncthreads();
    }
    int pre = ts[t] - s;
    rpl[2 * t] = pre; rpl[2 * t + 1] = pre + a;
    __syncthreads();
    int lim = nSeg - nodeBase; if (lim > 1024) lim = 1024;
    for (int i = t; i < lim; i += 512) {
        int abs0 = outBeg + rpl[i];
        rp[nodeBase + i] = abs0;
        cnt[i] = abs0;
    }
    if (last && t == 0) rp[nSeg] = outEnd;
    __syncthreads();
    for (int e = inBeg + t; e < inBeg + m; e += 512) {
        int2 p = bin[e];
        int pos = atomicAdd(&cnt[p.x - nodeBase], 1);
        colAll[pos] = p.y;
    }
}

// ===== colPair: (col, asgn[col]) per e0/e1 CSR slot =====
__global__ void colpair_kernel(const int* __restrict__ colAll,
                               const int* __restrict__ a01, const int* __restrict__ a12,
                               int2* __restrict__ colPair) {
    int i = blockIdx.x * blockDim.x + threadIdx.x;   // grid covers exactly E0+E1
    int c = colAll[i];
    int up = (i < E0) ? a01[c] : a12[c];
    colPair[i] = make_int2(c, up);
}

// ===== helpers =====
__device__ __forceinline__ unsigned short f2bf(float f) {   // RNE pack
    unsigned u = __float_as_uint(f);
    u += 0x7FFFu + ((u >> 16) & 1u);
    return (unsigned short)(u >> 16);
}
__device__ __forceinline__ float bf2f(unsigned short s) {
    return __uint_as_float((unsigned)s << 16);
}
__device__ __forceinline__ float4 ldbf4(const unsigned short* p) {
    ushort4 u = *reinterpret_cast<const ushort4*>(p);
    return make_float4(bf2f(u.x), bf2f(u.y), bf2f(u.z), bf2f(u.w));
}
__device__ __forceinline__ void stbf4(unsigned short* p, const float4& v) {
    ushort4 u; u.x = f2bf(v.x); u.y = f2bf(v.y); u.z = f2bf(v.z); u.w = f2bf(v.w);
    *reinterpret_cast<ushort4*>(p) = u;
}
__device__ __forceinline__ void fma4(float4& a, float s, const float4& b) {
    a.x = fmaf(s, b.x, a.x); a.y = fmaf(s, b.y, a.y);
    a.z = fmaf(s, b.z, a.z); a.w = fmaf(s, b.w, a.w);
}
__device__ __forceinline__ void red4(float4& s, int m) {
    s.x += __shfl_xor(s.x, m, 64);
    s.y += __shfl_xor(s.y, m, 64);
    s.z += __shfl_xor(s.z, m, 64);
    s.w += __shfl_xor(s.w, m, 64);
}
__device__ __forceinline__ void add4(float4& a, const float4& b) {
    a.x += b.x; a.y += b.y; a.z += b.z; a.w += b.w;
}

// ===== fp32 -> bf16 streaming convert (x0 -> xb0) =====
__global__ void cvt_bf16(const float* __restrict__ in, unsigned short* __restrict__ out, int n4) {
    int i = blockIdx.x * blockDim.x + threadIdx.x;
    if (i < n4) {
        float4 v = reinterpret_cast<const float4*>(in)[i];
        stbf4(&out[(size_t)i * 4], v);
    }
}

// ===== fused SAGE, barrier-free; bf16 features in/out, fp32 accumulate =====

template<int DIN, int DOUT>
__global__ __launch_bounds__(512) void sage_b(const unsigned short* __restrict__ x,
                       const int* __restrict__ rp, const int* __restrict__ col,
                       const float* __restrict__ Ws, const float* __restrict__ Wn,
                       const float* __restrict__ bias, unsigned short* __restrict__ h, int n) {
    constexpr int NW  = 8;
    constexpr int NPB = 64;
    constexpr int L4  = DIN / 4;
    constexpr int EPA = 64 / L4;
    constexpr int SD  = DIN + 4;
    constexpr int JQ  = DOUT / 4;
    constexpr int NDP = 64 / JQ;
    constexpr int NSL = NW / NDP;
    __shared__ float xsh[NPB][SD];
    __shared__ float msh[NPB][SD];
    const int wave = threadIdx.x >> 6;
    const int lane = threadIdx.x & 63;
    const int rowlane = lane % L4;
    const int esub = lane / L4;
    const int blockBase = blockIdx.x * NPB;
#pragma unroll
    for (int k = 0; k < NW; ++k) {
        const int kk = wave * NW + k;
        const int node = blockBase + kk;
        const int beg = rp[node], end = rp[node + 1];
        float4 own = make_float4(0.f, 0.f, 0.f, 0.f);
        if (lane < L4) own = ldbf4(&x[(size_t)node * DIN + lane * 4]);
        float4 s = make_float4(0.f, 0.f, 0.f, 0.f);
#pragma unroll 2
        for (int e = beg + esub; e < end; e += EPA) {
            const int c = col[e];
            const float4 v = ldbf4(&x[(size_t)c * DIN + rowlane * 4]);
            add4(s, v);
        }
#pragma unroll
        for (int m = L4; m < 64; m <<= 1) red4(s, m);
        if (lane < L4) {
            float sc = (end > beg) ? 1.0f / (float)(end - beg) : 0.f;
            *reinterpret_cast<float4*>(&msh[kk][lane * 4]) =
                make_float4(s.x * sc, s.y * sc, s.z * sc, s.w * sc);
            *reinterpret_cast<float4*>(&xsh[kk][lane * 4]) = own;
        }
    }
    asm volatile("s_waitcnt lgkmcnt(0)" ::: "memory");
    __builtin_amdgcn_wave_barrier();
    const int jq = lane % JQ;
    const int nd = lane / JQ;
    const float4 bv = *reinterpret_cast<const float4*>(&bias[jq * 4]);
    float4 acc[NSL];
#pragma unroll
    for (int sl = 0; sl < NSL; ++sl) acc[sl] = bv;
#pragma unroll 2
    for (int i = 0; i < DIN; i += 4) {
        const float4 w0 = *reinterpret_cast<const float4*>(&Ws[(i + 0) * DOUT + jq * 4]);
        const float4 w1 = *reinterpret_cast<const float4*>(&Ws[(i + 1) * DOUT + jq * 4]);
        const float4 w2 = *reinterpret_cast<const float4*>(&Ws[(i + 2) * DOUT + jq * 4]);
        const float4 w3 = *reinterpret_cast<const float4*>(&Ws[(i + 3) * DOUT + jq * 4]);
        const float4 u0 = *reinterpret_cast<const float4*>(&Wn[(i + 0) * DOUT + jq * 4]);
        const float4 u1 = *reinterpret_cast<const float4*>(&Wn[(i + 1) * DOUT + jq * 4]);
        const float4 u2 = *reinterpret_cast<const float4*>(&Wn[(i + 2) * DOUT + jq * 4]);
        const float4 u3 = *reinterpret_cast<const float4*>(&Wn[(i + 3) * DOUT + jq * 4]);
#pragma unroll
        for (int sl = 0; sl < NSL; ++sl) {
            const int kk = wave * NW + sl * NDP + nd;
            const float4 xv = *reinterpret_cast<const float4*>(&xsh[kk][i]);
            const float4 mv = *reinterpret_cast<const float4*>(&msh[kk][i]);
            fma4(acc[sl], xv.x, w0); fma4(acc[sl], xv.y, w1);
            fma4(acc[sl], xv.z, w2); fma4(acc[sl], xv.w, w3);
            fma4(acc[sl], mv.x, u0); fma4(acc[sl], mv.y, u1);
            fma4(acc[sl], mv.z, u2); fma4(acc[sl], mv.w, u3);
        }
    }
#pragma unroll
    for (int sl = 0; sl < NSL; ++sl) {
        const int kk = wave * NW + sl * NDP + nd;
        float4 o = make_float4(tanhf(acc[sl].x), tanhf(acc[sl].y),
                               tanhf(acc[sl].z), tanhf(acc[sl].w));
        stbf4(&h[(size_t)(blockBase + kk) * DOUT + jq * 4], o);
    }
}

// ===== fused concat+SAGE for up-layers (node-major, colPair); bf16 in/out =====

template<int DOUT>
__global__ __launch_bounds__(512) void sage_cat(const unsigned short* __restrict__ xup,
                       const int* __restrict__ asgn, const unsigned short* __restrict__ xlo,
                       const int* __restrict__ rp, const int2* __restrict__ colPair,
                       const float* __restrict__ Ws, const float* __restrict__ Wn,
                       const float* __restrict__ bias, unsigned short* __restrict__ h, int n) {
    constexpr int DIN = 64;
    constexpr int NW  = 8;
    constexpr int NPB = 64;
    constexpr int L4  = 16;
    constexpr int EPA = 4;
    constexpr int SD  = DIN + 4;
    constexpr int JQ  = DOUT / 4;
    constexpr int NDP = 64 / JQ;
    constexpr int NSL = NW / NDP;
    __shared__ float xsh[NPB][SD];
    __shared__ float msh[NPB][SD];
    const int wave = threadIdx.x >> 6;
    const int lane = threadIdx.x & 63;
    const int rowlane = lane % L4;
    const int esub = lane / L4;
    const int up = (rowlane < 8);
    const int sub4 = (rowlane & 7) * 4;
    const int blockBase = blockIdx.x * NPB;
#pragma unroll
    for (int k = 0; k < NW; ++k) {
        const int kk = wave * NW + k;
        const int node = blockBase + kk;
        const int beg = rp[node], end = rp[node + 1];
        const unsigned short* base = up ? xup : xlo;
        float4 own = make_float4(0.f, 0.f, 0.f, 0.f);
        if (lane < L4) {
            int cc = up ? asgn[node] : node;
            own = ldbf4(&base[(size_t)cc * 32 + sub4]);
        }
        float4 s = make_float4(0.f, 0.f, 0.f, 0.f);
#pragma unroll 2
        for (int e = beg + esub; e < end; e += EPA) {
            const int2 p = colPair[e];
            const int cc = up ? p.y : p.x;
            const float4 v = ldbf4(&base[(size_t)cc * 32 + sub4]);
            add4(s, v);
        }
#pragma unroll
        for (int m = L4; m < 64; m <<= 1) red4(s, m);
        if (lane < L4) {
            float sc = (end > beg) ? 1.0f / (float)(end - beg) : 0.f;
            *reinterpret_cast<float4*>(&msh[kk][lane * 4]) =
                make_float4(s.x * sc, s.y * sc, s.z * sc, s.w * sc);
            *reinterpret_cast<float4*>(&xsh[kk][lane * 4]) = own;
        }
    }
    asm volatile("s_waitcnt lgkmcnt(0)" ::: "memory");
    __builtin_amdgcn_wave_barrier();
    const int jq = lane % JQ;
    const int nd = lane / JQ;
    const float4 bv = *reinterpret_cast<const float4*>(&bias[jq * 4]);
    float4 acc[NSL];
#pragma unroll
    for (int sl = 0; sl < NSL; ++sl) acc[sl] = bv;
#pragma unroll 2
    for (int i = 0; i < DIN; i += 4) {
        const float4 w0 = *reinterpret_cast<const float4*>(&Ws[(i + 0) * DOUT + jq * 4]);
        const float4 w1 = *reinterpret_cast<const float4*>(&Ws[(i + 1) * DOUT + jq * 4]);
        const float4 w2 = *reinterpret_cast<const float4*>(&Ws[(i + 2) * DOUT + jq * 4]);
        const float4 w3 = *reinterpret_cast<const float4*>(&Ws[(i + 3) * DOUT + jq * 4]);
        const float4 u0 = *reinterpret_cast<const float4*>(&Wn[(i + 0) * DOUT + jq * 4]);
        const float4 u1 = *reinterpret_cast<const float4*>(&Wn[(i + 1) * DOUT + jq * 4]);
        const float4 u2 = *reinterpret_cast<const float4*>(&Wn[(i + 2) * DOUT + jq * 4]);
        const float4 u3 = *reinterpret_cast<const float4*>(&Wn[(i + 3) * DOUT + jq * 4]);
#pragma unroll
        for (int sl = 0; sl < NSL; ++sl) {
            const int kk = wave * NW + sl * NDP + nd;
            const float4 xv = *reinterpret_cast<const float4*>(&xsh[kk][i]);
            const float4 mv = *reinterpret_cast<const float4*>(&msh[kk][i]);
            fma4(acc[sl], xv.x, w0); fma4(acc[sl], xv.y, w1);
            fma4(acc[sl], xv.z, w2); fma4(acc[sl], xv.w, w3);
            fma4(acc[sl], mv.x, u0); fma4(acc[sl], mv.y, u1);
            fma4(acc[sl], mv.z, u2); fma4(acc[sl], mv.w, u3);
        }
    }
#pragma unroll
    for (int sl = 0; sl < NSL; ++sl) {
        const int kk = wave * NW + sl * NDP + nd;
        float4 o = make_float4(tanhf(acc[sl].x), tanhf(acc[sl].y),
                               tanhf(acc[sl].z), tanhf(acc[sl].w));
        stbf4(&h[(size_t)(blockBase + kk) * DOUT + jq * 4], o);
    }
}

// ===== pooling mean via CSR gather (bf16 in/out) =====

template<int F>
__global__ void csr_mean(const unsigned short* __restrict__ x, const int* __restrict__ rp,
                         const int* __restrict__ col, unsigned short* __restrict__ out, int n) {
    constexpr int G = 32, L4 = F / 4, EP = G / L4;
    int g = threadIdx.x / G, tg = threadIdx.x % G;
    int rowlane = tg % L4, esub = tg / L4;
    int seg = blockIdx.x * (256 / G) + g;
    if (seg >= n) return;
    int beg = rp[seg], end = rp[seg + 1];
    float4 s = make_float4(0.f, 0.f, 0.f, 0.f);
#pragma unroll 2
    for (int e = beg + esub; e < end; e += EP) {
        int c = col[e];
        const float4 v = ldbf4(&x[(size_t)c * F + rowlane * 4]);
        add4(s, v);
    }
#pragma unroll
    for (int m = L4; m < G; m <<= 1) red4(s, m);
    if (esub == 0) {
        float sc = (end > beg) ? 1.0f / (float)(end - beg) : 0.f;
        stbf4(&out[(size_t)seg * F + rowlane * 4],
              make_float4(s.x * sc, s.y * sc, s.z * sc, s.w * sc));
    }
}

// ===== fused conn-max + MLP (h0b bf16) =====

__global__ __launch_bounds__(512) void mlp_kernel(const unsigned short* __restrict__ h0b,
                           const int* __restrict__ rp, const int* __restrict__ col,
                           const float* __restrict__ xnet,
                           const float* __restrict__ w1, const float* __restrict__ b1,
                           const float* __restrict__ w2, const float* __restrict__ b2,
                           float* __restrict__ out) {
    constexpr int SD = 84;
    __shared__ float w1T[64 * SD];
    __shared__ float w2s[64];
    __shared__ float xin[8][SD];
    for (int idx = threadIdx.x; idx < 80 * 64; idx += 512) {
        int i = idx / 64, j = idx % 64;
        w1T[j * SD + i] = w1[idx];
    }
    if (threadIdx.x < 64) w2s[threadIdx.x] = w2[threadIdx.x];
    __syncthreads();
    int wv = threadIdx.x >> 6;
    int lane = threadIdx.x & 63;
    int rowlane = lane & 15, esub = lane >> 4;
    for (int r = 0; r < 4; ++r) {
        int net = blockIdx.x * 32 + r * 8 + wv;
        int beg = rp[net], end = rp[net + 1];
        float4 m = make_float4(-INFINITY, -INFINITY, -INFINITY, -INFINITY);
#pragma unroll 2
        for (int e = beg + esub; e < end; e += 4) {
            int c = col[e];
            const float4 v = ldbf4(&h0b[(size_t)c * 64 + rowlane * 4]);
            m.x = fmaxf(m.x, v.x); m.y = fmaxf(m.y, v.y);
            m.z = fmaxf(m.z, v.z); m.w = fmaxf(m.w, v.w);
        }
#pragma unroll
        for (int msk = 16; msk < 64; msk <<= 1) {
            m.x = fmaxf(m.x, __shfl_xor(m.x, msk, 64));
            m.y = fmaxf(m.y, __shfl_xor(m.y, msk, 64));
            m.z = fmaxf(m.z, __shfl_xor(m.z, msk, 64));
            m.w = fmaxf(m.w, __shfl_xor(m.w, msk, 64));
        }
        if (beg == end) m = make_float4(0.f, 0.f, 0.f, 0.f);
        if (esub == 0) *reinterpret_cast<float4*>(&xin[wv][rowlane * 4]) = m;
        else if (esub == 1) xin[wv][64 + rowlane] = xnet[(size_t)net * 16 + rowlane];
        float acc = b1[lane];
#pragma unroll
        for (int i = 0; i < 80; i += 4) {
            const float4 w4 = *reinterpret_cast<const float4*>(&w1T[lane * SD + i]);
            const float4 xv = *reinterpret_cast<const float4*>(&xin[wv][i]);
            acc += xv.x * w4.x + xv.y * w4.y + xv.z * w4.z + xv.w * w4.w;
        }
        float p = tanhf(acc) * w2s[lane];
#pragma unroll
        for (int off = 32; off > 0; off >>= 1) p += __shfl_down(p, off, 64);
        if (lane == 0) out[net] = p + b2[0];
    }
}

// ===== host =====

extern "C" void kernel_launch(void* const* d_in, const int* in_sizes, int n_in,
                              void* d_out, int out_size, void* d_ws, size_t ws_size,
                              hipStream_t stream) {
    (void)in_sizes; (void)n_in; (void)out_size; (void)ws_size;
    const float* x0   = (const float*)d_in[0];
    const float* xnet = (const float*)d_in[1];
    const float* Ws0 = (const float*)d_in[2];  const float* Wn0 = (const float*)d_in[3];  const float* b0 = (const float*)d_in[4];
    const float* Ws1 = (const float*)d_in[5];  const float* Wn1 = (const float*)d_in[6];  const float* b1 = (const float*)d_in[7];
    const float* Ws2 = (const float*)d_in[8];  const float* Wn2 = (const float*)d_in[9];  const float* b2 = (const float*)d_in[10];
    const float* Ws3 = (const float*)d_in[11]; const float* Wn3 = (const float*)d_in[12]; const float* b3 = (const float*)d_in[13];
    const float* Ws4 = (const float*)d_in[14]; const float* Wn4 = (const float*)d_in[15]; const float* b4 = (const float*)d_in[16];
    const float* mw1 = (const float*)d_in[17]; const float* mb1 = (const float*)d_in[18];
    const float* mw2 = (const float*)d_in[19]; const float* mb2 = (const float*)d_in[20];
    const int* e0s = (const int*)d_in[21]; const int* e0d = (const int*)d_in[22];
    const int* e1s = (const int*)d_in[23]; const int* e1d = (const int*)d_in[24];
    const int* e2s = (const int*)d_in[25]; const int* e2d = (const int*)d_in[26];
    const int* a01 = (const int*)d_in[27]; const int* a12 = (const int*)d_in[28];
    const int* cs  = (const int*)d_in[29]; const int* cd  = (const int*)d_in[30];

    char* ws = (char*)d_ws;
    const size_t MB = 1u << 20;
    int* rp0    = (int*)(ws + (size_t)(0.00 * MB));
    int* rp1    = (int*)(ws + (size_t)(1.25 * MB));
    int* rp2    = (int*)(ws + (size_t)(1.75 * MB));
    int* rpA01  = (int*)(ws + (size_t)(2.00 * MB));
    int* rpA12  = (int*)(ws + (size_t)(2.50 * MB));
    int* rpC    = (int*)(ws + (size_t)(2.75 * MB));
    int* cntg   = (int*)(ws + (size_t)(3.75 * MB));            // 612 ints
    int* bs     = (int*)(ws + (size_t)(3.75 * MB) + 4096);     // 613 ints
    int* colAll = (int*)(ws + (size_t)(4.00 * MB));     // 14.8MB -> ends ~18.8
    int2* colPair = (int2*)(ws + 19 * MB);              // 21MB -> 40
    unsigned short* xb0 = (unsigned short*)(ws + 41 * MB);  // N0*16 bf16 = 8MB  -> 49
    unsigned short* h0  = (unsigned short*)(ws + 49 * MB);  // N0*32 bf16 = 16MB -> 65
    unsigned short* h1  = (unsigned short*)(ws + 65 * MB);  // 4MB  -> 69
    unsigned short* h2  = (unsigned short*)(ws + 69 * MB);  // 1MB  -> 70
    unsigned short* x1  = (unsigned short*)(ws + 70 * MB);  // 4MB  -> 74
    unsigned short* x2  = (unsigned short*)(ws + 74 * MB);  // 1MB  -> 75
    unsigned short* h1b = (unsigned short*)(ws + 75 * MB);  // 4MB  -> 79
    unsigned short* h0b = (unsigned short*)(ws + 79 * MB);  // N0*64 bf16 = 32MB -> 111
    int2* bin   = (int2*)(ws + 111 * MB);   // padded: 612*10240*8B = 47.8MB -> ~159MB (build-only)

    // ---- binned CSR build: padded bin, no bcount pass ----
    hipMemsetAsync(cntg, 0, NBK_TOT * 4, stream);
    bscatter<<<dim3(CBT), 256, 0, stream>>>(e0s, e0d, e1s, e1d, e2s, e2d, a01, a12, cs, cd,
                                            cntg, bin);
    bscan<<<dim3(1), 1024, 0, stream>>>(cntg, bs);
    bbuild<<<dim3(NBK_TOT), 512, 0, stream>>>(bin, bs, colAll,
                                              rp0, rp1, rp2, rpA01, rpA12, rpC);
    colpair_kernel<<<dim3((E0 + E1) / 256), 256, 0, stream>>>(colAll, a01, a12, colPair);
    // x0 -> bf16 copy (gather working set 16MB -> 8MB)
    cvt_bf16<<<dim3(N0 * 16 / 4 / 256), 256, 0, stream>>>(x0, xb0, N0 * 16 / 4);

    // ---- layer 0: h0 = sage(x0, e0)  [N0,32] bf16
    sage_b<16, 32><<<dim3(N0 / 64), 512, 0, stream>>>(xb0, rp0, colAll, Ws0, Wn0, b0, h0, N0);
    // ---- pool 0->1: x1 = seg_mean(h0, assign01)  [N1,32] bf16
    csr_mean<32><<<dim3(N1 / 8), 256, 0, stream>>>(h0, rpA01, colAll, x1, N1);
    // ---- layer 1: h1 = sage(x1, e1)  [N1,32] bf16
    sage_b<32, 32><<<dim3(N1 / 64), 512, 0, stream>>>(x1, rp1, colAll, Ws1, Wn1, b1, h1, N1);
    // ---- pool 1->2: x2 = seg_mean(h1, assign12)  [N2,32] bf16
    csr_mean<32><<<dim3(N2 / 8), 256, 0, stream>>>(h1, rpA12, colAll, x2, N2);
    // ---- layer 2: h2 = sage(x2, e2)  [N2,32] bf16
    sage_b<32, 32><<<dim3(N2 / 64), 512, 0, stream>>>(x2, rp2, colAll, Ws2, Wn2, b2, h2, N2);
    // ---- up 2->1: h1b = sage([h2[a12[.]], h1], e1)  [N1,32] bf16
    sage_cat<32><<<dim3(N1 / 64), 512, 0, stream>>>(h2, a12, h1, rp1, colPair,
                                                    Ws3, Wn3, b3, h1b, N1);
    // ---- up 1->0: h0b = sage([h1b[a01[.]], h0], e0)  [N0,64] bf16
    sage_cat<64><<<dim3(N0 / 64), 512, 0, stream>>>(h1b, a01, h0, rp0, colPair,
                                                    Ws4, Wn4, b4, h0b, N0);
    // ---- fused per-net segment-max + MLP -> out [NNET,1]
    mlp_kernel<<<dim3(NNET / 32), 512, 0, stream>>>(h0b, rpC, colAll, xnet, mw1, mb1, mw2, mb2,
                                                    (float*)d_out);
}